// Round 4
// baseline (370.987 us; speedup 1.0000x reference)
//
#include <hip/hip_runtime.h>
#include <hip/hip_bf16.h>

#define N_B 1024
#define N_ITEMS 100000
#define N_CLUSTERS 10
#define N_D 64
#define MAXT 6272            // padded tile capacity; NT <= 6260 always
#define K1B 392              // segsum blocks: 392*4 waves*64 rows = 100352
#define W2PB 1563            // w2p blocks: 1563*64 = 100032 cols
#define K3BY 96              // k3 grid: 16 x 96 = 1536 = 6 blocks/CU exactly
#define NGW 384              // 96 by * 4 waves; tiles/wave = 6272/384 = 16.33

typedef __attribute__((ext_vector_type(8))) short short8;
typedef __attribute__((ext_vector_type(4))) float f32x4;

#if defined(__has_builtin)
#if __has_builtin(__builtin_amdgcn_exp2f)
#define EXP2F(x) __builtin_amdgcn_exp2f(x)
#endif
#endif
#ifndef EXP2F
#define EXP2F(x) exp2f(x)
#endif

#define MFMA(a, b, c) __builtin_amdgcn_mfma_f32_16x16x32_bf16(a, b, c, 0, 0, 0)

// bf16 RNE split helpers (bit-level; sign-safe)
__device__ __forceinline__ unsigned short bf16_rne(float x) {
  unsigned u = __float_as_uint(x);
  u += 0x7FFFu + ((u >> 16) & 1u);
  return (unsigned short)(u >> 16);
}
__device__ __forceinline__ float bf16_f(unsigned short b) {
  return __uint_as_float(((unsigned)b) << 16);
}

// ---------------------------------------------------------------------------
// Kernel A (fused): blocks [0,392) = per-block partial S1/counts + inv zero;
// blocks [392,1955) = W2 transpose into SPLIT bf16 hi/lo planes (item-major).
// ---------------------------------------------------------------------------
__global__ __launch_bounds__(256) void kA(
    const int* __restrict__ cl, const float* __restrict__ W1,
    const float* __restrict__ W2, float* __restrict__ S1p,
    float* __restrict__ cntp, int* __restrict__ inv,
    unsigned short* __restrict__ W2Ph, unsigned short* __restrict__ W2Pl) {
  __shared__ float smem[64 * 65];              // 16.6 KB; segsum uses 2600
  int t = threadIdx.x;
  if (blockIdx.x < K1B) {
    // ---- segsum ----
    float (*s1)[N_CLUSTERS][N_D] = (float (*)[N_CLUSTERS][N_D])smem;
    float (*scnt)[N_CLUSTERS] =
        (float (*)[N_CLUSTERS])(smem + 4 * N_CLUSTERS * N_D);
    int wave = t >> 6, lane = t & 63;

    inv[blockIdx.x * 256 + t] = 0;             // zero all MAXT*16 slots

    float a[N_CLUSTERS], cn[N_CLUSTERS];
#pragma unroll
    for (int k = 0; k < N_CLUSTERS; ++k) { a[k] = 0.f; cn[k] = 0.f; }

    int gw = blockIdx.x * 4 + wave;
    int r0 = gw * 64;
#pragma unroll 1
    for (int b = 0; b < 8; ++b) {
      int i0 = r0 + b * 8;
      float w[8];
      int c[8];
      if (i0 + 8 <= N_ITEMS) {
#pragma unroll
        for (int j = 0; j < 8; ++j) {
          c[j] = cl[i0 + j];                   // wave-uniform -> s_load
          w[j] = W1[(size_t)(i0 + j) * N_D + lane];
        }
      } else {
#pragma unroll
        for (int j = 0; j < 8; ++j) {
          int i = i0 + j;
          bool ok = i < N_ITEMS;
          c[j] = ok ? cl[i] : -1;
          w[j] = ok ? W1[(size_t)i * N_D + lane] : 0.f;
        }
      }
#pragma unroll
      for (int j = 0; j < 8; ++j)
#pragma unroll
        for (int k = 0; k < N_CLUSTERS; ++k) {
          bool m = (c[j] == k);
          a[k] += m ? w[j] : 0.f;
          cn[k] += m ? 1.f : 0.f;
        }
    }
#pragma unroll
    for (int k = 0; k < N_CLUSTERS; ++k) s1[wave][k][lane] = a[k];
    if (lane == 0) {
#pragma unroll
      for (int k = 0; k < N_CLUSTERS; ++k) scnt[wave][k] = cn[k];
    }
    __syncthreads();
    const float* fs1 = smem;
    for (int i = t; i < N_CLUSTERS * N_D; i += 256) {
      S1p[blockIdx.x * 640 + i] =
          fs1[i] + fs1[640 + i] + fs1[1280 + i] + fs1[1920 + i];
    }
    if (t < N_CLUSTERS) {
      cntp[blockIdx.x * N_CLUSTERS + t] =
          scnt[0][t] + scnt[1][t] + scnt[2][t] + scnt[3][t];
    }
  } else {
    // ---- w2p: transpose + split-plane bf16 hi/lo ----
    float (*tile)[65] = (float (*)[65])smem;   // +1 pad: conflict-free
    int blk = blockIdx.x - K1B;
    int c0 = blk * 64;
    int cl_ = t & 63;
    int r0 = t >> 6;
    bool okr = (c0 + cl_) < N_ITEMS;
#pragma unroll
    for (int rr = 0; rr < 16; ++rr) {
      int r = rr * 4 + r0;
      tile[cl_][r] = okr ? W2[(size_t)r * N_ITEMS + c0 + cl_] : 0.f;
    }
    __syncthreads();
#pragma unroll
    for (int itw = 0; itw < 8; ++itw) {
      int task = itw * 256 + t;                // 2048 tasks: (col, dpair)
      int c_l = task >> 5, dp = task & 31;
      int c = c0 + c_l;
      if (c < N_ITEMS) {
        float v0 = tile[c_l][dp * 2], v1 = tile[c_l][dp * 2 + 1];
        unsigned short h0 = bf16_rne(v0), h1 = bf16_rne(v1);
        unsigned short l0 = bf16_rne(v0 - bf16_f(h0));
        unsigned short l1 = bf16_rne(v1 - bf16_f(h1));
        ((unsigned*)W2Ph)[(size_t)c * 32 + dp] =
            (unsigned)h0 | ((unsigned)h1 << 16);
        ((unsigned*)W2Pl)[(size_t)c * 32 + dp] =
            (unsigned)l0 | ((unsigned)l1 << 16);
      }
    }
  }
}

// ---------------------------------------------------------------------------
// Kernel 1r (11 blocks — fixes the R3 regression where the S1g reduce sat
// serialized on one CU for ~35-40us):
//   block 0: cursor zero + parallel count reduce + segment bases + tinfo
//   blocks 1..10: S1g reduce, 64 cols each, 4 waves x 98 coalesced loads
// ---------------------------------------------------------------------------
__global__ __launch_bounds__(256) void k1r(
    const float* __restrict__ S1p, const float* __restrict__ cntp,
    float* __restrict__ S1g, float* __restrict__ cntF, int* __restrict__ meta,
    int* __restrict__ tinfo, int* __restrict__ cursor) {
  int t = threadIdx.x;
  if (blockIdx.x > 0) {                        // ---- S1g chunk reduce ----
    __shared__ float sgp[4][64];
    int wave = t >> 6, lane = t & 63;
    int col = (blockIdx.x - 1) * 64 + lane;
    float s = 0.f;
    const float* sp = S1p + col;
#pragma unroll 4
    for (int b = wave; b < K1B; b += 4) s += sp[b * 640];
    sgp[wave][lane] = s;
    __syncthreads();
    if (t < 64) {
      S1g[(blockIdx.x - 1) * 64 + t] =
          sgp[0][t] + sgp[1][t] + sgp[2][t] + sgp[3][t];
    }
    return;
  }
  __shared__ int baseS[11];
  __shared__ int cntI[N_CLUSTERS];
  __shared__ float part[16][N_CLUSTERS];
  if (t < 16) cursor[t] = 0;
  if (t < 160) {                               // coalesced count reduce
    int c = t % N_CLUSTERS, g = t / N_CLUSTERS;
    float s = 0.f;
    for (int b = g; b < K1B; b += 16) s += cntp[b * N_CLUSTERS + c];
    part[g][c] = s;
  }
  __syncthreads();
  if (t < N_CLUSTERS) {
    float s = 0.f;
#pragma unroll
    for (int g = 0; g < 16; ++g) s += part[g][t];
    cntF[t] = s;
    cntI[t] = (int)(s + 0.5f);
  }
  __syncthreads();
  if (t == 0) {
    int acc = 0;
    for (int c = 0; c < N_CLUSTERS; ++c) {
      baseS[c] = acc;
      acc += ((cntI[c] + 15) >> 4) << 4;       // 16-align each segment
    }
    baseS[10] = acc;
    for (int c = 0; c < 11; ++c) meta[c] = baseS[c];
    meta[11] = acc >> 4;                       // NT
  }
  __syncthreads();
  int NT = baseS[10] >> 4;
  for (int jt = t; jt < MAXT; jt += 256) {
    int c = 0, nv = 0;
    if (jt < NT) {
      int p0 = jt * 16;
      for (int k = 0; k < N_CLUSTERS; ++k)
        if (p0 >= baseS[k] && p0 < baseS[k + 1]) c = k;
      nv = min(16, cntI[c] - (p0 - baseS[c]));
      if (nv < 0) nv = 0;
    }
    tinfo[jt] = c | (nv << 8);
  }
}

// ---------------------------------------------------------------------------
// Kernel B (fused): blocks [0,391) = inverse perm + bucket zero;
// blocks [391,423) = A-fragment precompute (h = inp @ S1g, *log2e, RNE
// hi/lo split, MFMA A layout) -> hfrag, computed ONCE.
// ---------------------------------------------------------------------------
__global__ __launch_bounds__(256) void kB(
    const int* __restrict__ cl, const int* __restrict__ meta,
    int* __restrict__ cursor, int* __restrict__ inv,
    const float* __restrict__ inp, const float* __restrict__ S1g,
    short8* __restrict__ hfrag, float* __restrict__ bucket) {
  __shared__ int wn[4][N_CLUSTERS];
  __shared__ int bb[N_CLUSTERS];
  int t = threadIdx.x;
  if (blockIdx.x < 391) {
    int i = blockIdx.x * 256 + t;
    if (i < N_B * N_CLUSTERS) bucket[i] = 0.f;
    int wave = t >> 6, lane = t & 63;
    int c = (i < N_ITEMS) ? cl[i] : -1;
    unsigned long long m[N_CLUSTERS];
#pragma unroll
    for (int k = 0; k < N_CLUSTERS; ++k) {
      m[k] = __ballot(c == k);
      if (lane == 0) wn[wave][k] = __popcll(m[k]);
    }
    __syncthreads();
    if (t < N_CLUSTERS) {
      int tot = wn[0][t] + wn[1][t] + wn[2][t] + wn[3][t];
      bb[t] = tot ? atomicAdd(&cursor[t], tot) : 0;
    }
    __syncthreads();
    if (c >= 0) {
      int rank = 0;
#pragma unroll
      for (int k = 0; k < N_CLUSTERS; ++k)
        if (c == k) rank = __popcll(m[k] & ((1ull << lane) - 1ull));
      int wsum = 0;
      for (int w2 = 0; w2 < wave; ++w2) wsum += wn[w2][c];
      inv[meta[c] + bb[c] + wsum + rank] = i;
    }
  } else {
    int id = (blockIdx.x - 391) * 256 + t;     // 8192 (bx,rt,ks,lane) tuples
    int lane = id & 63;
    int ks = (id >> 6) & 1;
    int rt = (id >> 7) & 3;
    int bx = id >> 9;
    int row = bx * 64 + rt * 16 + (lane & 15);
    int d0 = ks * 32 + (lane >> 4) * 8;
    float hv[8];
#pragma unroll
    for (int j = 0; j < 8; ++j) hv[j] = 0.f;
#pragma unroll
    for (int c = 0; c < N_CLUSTERS; ++c) {
      float ic = inp[row * N_CLUSTERS + c];
      const float* sp = S1g + c * N_D + d0;
#pragma unroll
      for (int j = 0; j < 8; ++j) hv[j] += ic * sp[j];
    }
    short8 hi8, lo8;
#pragma unroll
    for (int j = 0; j < 8; ++j) {
      float x = hv[j] * 1.44269504088896340736f;   // fold log2(e) -> exp2
      unsigned short us = bf16_rne(x);
      hi8[j] = (short)us;
      lo8[j] = (short)bf16_rne(x - bf16_f(us));
    }
    int f0 = rt * 4 + ks * 2;
    hfrag[(bx * 16 + f0) * 64 + lane] = hi8;
    hfrag[(bx * 16 + f0 + 1) * 64 + lane] = lo8;
  }
}

// ---------------------------------------------------------------------------
// Kernel 3 (hot): register-resident A, split-plane B gather (loads ARE the
// MFMA operands), 1-deep register prefetch, readlane tinfo, atomic bucket.
// R4: 6 blocks/CU (grid 16x96, launch_bounds(256,6)) — R3's 3 blocks/CU
// gave only ~360 cyc of issuable work per SIMD per phase vs ~600 cyc gather
// latency (Occ 23.7%, both pipes idle). VGPR 76 <= 84 cap at 6 waves/EU.
// ---------------------------------------------------------------------------
__global__ __launch_bounds__(256, 6) void k3_mfma(
    const unsigned short* __restrict__ W2Ph,
    const unsigned short* __restrict__ W2Pl,
    const short8* __restrict__ hfrag, const int* __restrict__ inv,
    const int* __restrict__ tinfo, float* __restrict__ bucket) {
  __shared__ int linv[4][288];                 // 17*16=272 used, 4.6 KB
  int t = threadIdx.x;
  int wave = t >> 6, lane = t & 63;
  int l15 = lane & 15, quad = lane >> 4;

  // bijective XCD swizzle: 1536 = 8 XCDs x 192; each XCD gets 12 complete
  // by-groups (all 16 bx of a by share B tiles -> L2 hits)
  int lid = blockIdx.y * 16 + blockIdx.x;
  int nid = (lid & 7) * 192 + (lid >> 3);
  int bx = nid & 15, by = nid >> 4;            // by 0..95

  int gw = by * 4 + wave;                      // 0..383
  int jt0 = (MAXT * gw) / NGW;
  int nt = (MAXT * (gw + 1)) / NGW - jt0;      // 16 or 17

  // A fragments -> registers (invariant across this wave's tiles)
  short8 fr[16];
  {
    const short8* hp = hfrag + bx * 1024 + lane;
#pragma unroll
    for (int f = 0; f < 16; ++f) fr[f] = hp[f * 64];
  }
  // tinfo slice -> lane registers (readlane broadcast later)
  int tiv = tinfo[jt0 + ((lane < nt) ? lane : nt - 1)];
  // stage this wave's col slice into LDS
  {
    const int* ip = inv + jt0 * 16;
    int n = nt * 16;
    for (int i = lane; i < n; i += 64) linv[wave][i] = ip[i];
  }
  __syncthreads();

  f32x4 acc[4];
#pragma unroll
  for (int r = 0; r < 4; ++r) acc[r] = (f32x4){0.f, 0.f, 0.f, 0.f};

  short8 xh0, xl0, xh1, xl1, yh0, yl0, yh1, yl1;
  int cc, nv, colN;
  {
    int c0 = inv[jt0 * 16 + l15];
    int o = c0 * 64 + quad * 8;
    xh0 = *(const short8*)(W2Ph + o);
    xh1 = *(const short8*)(W2Ph + o + 32);
    xl0 = *(const short8*)(W2Pl + o);
    xl1 = *(const short8*)(W2Pl + o + 32);
    colN = inv[jt0 * 16 + 16 + l15];           // tile 1 (nt >= 16 always)
    int ti = __builtin_amdgcn_readlane(tiv, 0);
    cc = ti & 255;
    nv = ti >> 8;
  }

#define K3_FLUSH()                                                            \
  {                                                                           \
    _Pragma("unroll") for (int rt = 0; rt < 4; ++rt) {                        \
      float e0 = acc[rt][0], e1 = acc[rt][1];                                 \
      float e2 = acc[rt][2], e3 = acc[rt][3];                                 \
      _Pragma("unroll") for (int mm = 1; mm < 16; mm <<= 1) {                 \
        e0 += __shfl_xor(e0, mm, 64);                                         \
        e1 += __shfl_xor(e1, mm, 64);                                         \
        e2 += __shfl_xor(e2, mm, 64);                                         \
        e3 += __shfl_xor(e3, mm, 64);                                         \
      }                                                                       \
      if (l15 == 0) {                                                         \
        int r = bx * 64 + rt * 16 + quad * 4;                                 \
        atomicAdd(&bucket[(r + 0) * N_CLUSTERS + cc], e0);                    \
        atomicAdd(&bucket[(r + 1) * N_CLUSTERS + cc], e1);                    \
        atomicAdd(&bucket[(r + 2) * N_CLUSTERS + cc], e2);                    \
        atomicAdd(&bucket[(r + 3) * N_CLUSTERS + cc], e3);                    \
      }                                                                       \
      acc[rt] = (f32x4){0.f, 0.f, 0.f, 0.f};                                  \
    }                                                                         \
  }

#define K3_PHASE(CH0, CL0, CH1, CL1, NH0, NL0, NH1, NL1)                      \
  {                                                                           \
    int tin = __builtin_amdgcn_readlane(tiv, (it + 1 < nt) ? it + 1 : nt - 1);\
    int ccn = tin & 255, nvn = tin >> 8;                                      \
    {                                                                         \
      int o = colN * 64 + quad * 8;            /* prefetch tile it+1 */       \
      NH0 = *(const short8*)(W2Ph + o);                                       \
      NH1 = *(const short8*)(W2Ph + o + 32);                                  \
      NL0 = *(const short8*)(W2Pl + o);                                       \
      NL1 = *(const short8*)(W2Pl + o + 32);                                  \
    }                                                                         \
    colN = linv[wave][((it + 2 < nt) ? it + 2 : nt - 1) * 16 + l15];          \
    f32x4 cr[4];                                                              \
    _Pragma("unroll") for (int rt = 0; rt < 4; ++rt) {                        \
      f32x4 c = {0.f, 0.f, 0.f, 0.f};                                         \
      c = MFMA(fr[rt * 4 + 0], CH0, c);                                       \
      c = MFMA(fr[rt * 4 + 0], CL0, c);                                       \
      c = MFMA(fr[rt * 4 + 1], CH0, c);                                       \
      c = MFMA(fr[rt * 4 + 2], CH1, c);                                       \
      c = MFMA(fr[rt * 4 + 2], CL1, c);                                       \
      c = MFMA(fr[rt * 4 + 3], CH1, c);                                       \
      cr[rt] = c;                                                             \
    }                                                                         \
    if (nv == 16) {                                                           \
      _Pragma("unroll") for (int rt = 0; rt < 4; ++rt) {                      \
        acc[rt][0] += EXP2F(cr[rt][0]);                                       \
        acc[rt][1] += EXP2F(cr[rt][1]);                                       \
        acc[rt][2] += EXP2F(cr[rt][2]);                                       \
        acc[rt][3] += EXP2F(cr[rt][3]);                                       \
      }                                                                       \
    } else {                                                                  \
      _Pragma("unroll") for (int rt = 0; rt < 4; ++rt) {                      \
        acc[rt][0] += (l15 < nv) ? EXP2F(cr[rt][0]) : 0.f;                    \
        acc[rt][1] += (l15 < nv) ? EXP2F(cr[rt][1]) : 0.f;                    \
        acc[rt][2] += (l15 < nv) ? EXP2F(cr[rt][2]) : 0.f;                    \
        acc[rt][3] += (l15 < nv) ? EXP2F(cr[rt][3]) : 0.f;                    \
      }                                                                       \
    }                                                                         \
    if (it == nt - 1 || ccn != cc) K3_FLUSH();                                \
    cc = ccn;                                                                 \
    nv = nvn;                                                                 \
    ++it;                                                                     \
    if (it == nt) break;                                                      \
  }

  int it = 0;
  while (true) {
    K3_PHASE(xh0, xl0, xh1, xl1, yh0, yl0, yh1, yl1)
    K3_PHASE(yh0, yl0, yh1, yl1, xh0, xl0, xh1, xl1)
  }
#undef K3_PHASE
#undef K3_FLUSH
}

// ---------------------------------------------------------------------------
// Kernel 4: normalize (softmax denom = per-row sum over clusters), /counts.
// ---------------------------------------------------------------------------
__global__ __launch_bounds__(320) void k4_fin(
    const float* __restrict__ bucket, const float* __restrict__ cntF,
    float* __restrict__ out) {
  __shared__ float bl[32][N_CLUSTERS];
  int t = threadIdx.x;                         // 0..319
  int r = t / N_CLUSTERS, c = t % N_CLUSTERS;
  int row = blockIdx.x * 32 + r;
  float s = bucket[row * N_CLUSTERS + c];
  bl[r][c] = s;
  __syncthreads();
  float tot = 0.f;
#pragma unroll
  for (int k = 0; k < N_CLUSTERS; ++k) tot += bl[r][k];
  out[row * N_CLUSTERS + c] = s / (tot * fmaxf(cntF[c], 1.f));
}

// ---------------------------------------------------------------------------
// Workspace layout (4-byte units), total 27.7 MB:
//   [0,640) S1g | [640,656) cntF | [656,672) meta | [672,688) cursor
//   [1024,7296) tinfo = cluster|(nv<<8) | [16384,116736) inv
//   [131072,196608) hfrag (256 KB, MFMA A layout, log2e folded)
//   [262144,3463168) W2Ph (bf16 hi plane, item-major)
//   [3463168,6664192) W2Pl (bf16 lo plane)
//   [6664192,6915072) S1p | [6915072,6918992) cntp
//   [6918992,6929232) bucket (atomic accum; zeroed in kB)
// No memset: inv zeroed by kA, cursor by k1r, bucket by kB.
// ---------------------------------------------------------------------------
extern "C" void kernel_launch(void* const* d_in, const int* in_sizes, int n_in,
                              void* d_out, int out_size, void* d_ws, size_t ws_size,
                              hipStream_t stream) {
  const float* input = (const float*)d_in[0];   // (1024, 10) f32
  const int* cl      = (const int*)d_in[1];     // (100000,) i32
  const float* W1    = (const float*)d_in[2];   // (100000, 64) f32
  const float* W2    = (const float*)d_in[3];   // (64, 100000) f32
  float* out = (float*)d_out;
  float* ws = (float*)d_ws;

  float* S1g            = ws;
  float* cntF           = ws + 640;
  int*   meta           = (int*)(ws + 656);
  int*   cursor         = (int*)(ws + 672);
  int*   tinfo          = (int*)(ws + 1024);
  int*   inv            = (int*)(ws + 16384);
  short8* hfrag         = (short8*)(ws + 131072);
  unsigned short* W2Ph  = (unsigned short*)(ws + 262144);
  unsigned short* W2Pl  = (unsigned short*)(ws + 3463168);
  float* S1p            = ws + 6664192;
  float* cntp           = ws + 6915072;
  float* bucket         = ws + 6918992;

  kA<<<K1B + W2PB, 256, 0, stream>>>(cl, W1, W2, S1p, cntp, inv, W2Ph, W2Pl);
  k1r<<<11, 256, 0, stream>>>(S1p, cntp, S1g, cntF, meta, tinfo, cursor);
  kB<<<391 + 32, 256, 0, stream>>>(cl, meta, cursor, inv, input, S1g, hfrag,
                                   bucket);
  dim3 g3(16, K3BY);                            // 1536 blocks = 6/CU exactly
  k3_mfma<<<g3, 256, 0, stream>>>(W2Ph, W2Pl, hfrag, inv, tinfo, bucket);
  k4_fin<<<32, 320, 0, stream>>>(bucket, cntF, out);
}

// Round 5
// 243.681 us; speedup vs baseline: 1.5224x; 1.5224x over previous
//
#include <hip/hip_runtime.h>
#include <hip/hip_bf16.h>

#define N_B 1024
#define N_ITEMS 100000
#define N_CLUSTERS 10
#define N_D 64
#define MAXT 6272            // padded tile capacity; NT <= 6260 always
#define K1B 392              // segsum blocks: 392*4 waves*64 rows = 100352
#define W2PB 1563            // w2p blocks: 1563*64 = 100032 cols
#define K3BY 96              // k3 grid: 16 x 96 = 1536 = 6 blocks/CU
#define NGW 384              // 96 by * 4 waves; tiles/wave = 6272/384 = 16.33

typedef __attribute__((ext_vector_type(8))) short short8;
typedef __attribute__((ext_vector_type(4))) float f32x4;

#if defined(__has_builtin)
#if __has_builtin(__builtin_amdgcn_exp2f)
#define EXP2F(x) __builtin_amdgcn_exp2f(x)
#endif
#endif
#ifndef EXP2F
#define EXP2F(x) exp2f(x)
#endif

#define MFMA(a, b, c) __builtin_amdgcn_mfma_f32_16x16x32_bf16(a, b, c, 0, 0, 0)

// bf16 RNE split helpers (bit-level; sign-safe)
__device__ __forceinline__ unsigned short bf16_rne(float x) {
  unsigned u = __float_as_uint(x);
  u += 0x7FFFu + ((u >> 16) & 1u);
  return (unsigned short)(u >> 16);
}
__device__ __forceinline__ float bf16_f(unsigned short b) {
  return __uint_as_float(((unsigned)b) << 16);
}

// ---------------------------------------------------------------------------
// Kernel A (fused): blocks [0,392) = per-block partial S1/counts + inv zero;
// blocks [392,1955) = W2 transpose into SPLIT bf16 hi/lo planes (item-major).
// ---------------------------------------------------------------------------
__global__ __launch_bounds__(256) void kA(
    const int* __restrict__ cl, const float* __restrict__ W1,
    const float* __restrict__ W2, float* __restrict__ S1p,
    float* __restrict__ cntp, int* __restrict__ inv,
    unsigned short* __restrict__ W2Ph, unsigned short* __restrict__ W2Pl) {
  __shared__ float smem[64 * 65];              // 16.6 KB; segsum uses 2600
  int t = threadIdx.x;
  if (blockIdx.x < K1B) {
    // ---- segsum ----
    float (*s1)[N_CLUSTERS][N_D] = (float (*)[N_CLUSTERS][N_D])smem;
    float (*scnt)[N_CLUSTERS] =
        (float (*)[N_CLUSTERS])(smem + 4 * N_CLUSTERS * N_D);
    int wave = t >> 6, lane = t & 63;

    inv[blockIdx.x * 256 + t] = 0;             // zero all MAXT*16 slots

    float a[N_CLUSTERS], cn[N_CLUSTERS];
#pragma unroll
    for (int k = 0; k < N_CLUSTERS; ++k) { a[k] = 0.f; cn[k] = 0.f; }

    int gw = blockIdx.x * 4 + wave;
    int r0 = gw * 64;
#pragma unroll 1
    for (int b = 0; b < 8; ++b) {
      int i0 = r0 + b * 8;
      float w[8];
      int c[8];
      if (i0 + 8 <= N_ITEMS) {
#pragma unroll
        for (int j = 0; j < 8; ++j) {
          c[j] = cl[i0 + j];                   // wave-uniform -> s_load
          w[j] = W1[(size_t)(i0 + j) * N_D + lane];
        }
      } else {
#pragma unroll
        for (int j = 0; j < 8; ++j) {
          int i = i0 + j;
          bool ok = i < N_ITEMS;
          c[j] = ok ? cl[i] : -1;
          w[j] = ok ? W1[(size_t)i * N_D + lane] : 0.f;
        }
      }
#pragma unroll
      for (int j = 0; j < 8; ++j)
#pragma unroll
        for (int k = 0; k < N_CLUSTERS; ++k) {
          bool m = (c[j] == k);
          a[k] += m ? w[j] : 0.f;
          cn[k] += m ? 1.f : 0.f;
        }
    }
#pragma unroll
    for (int k = 0; k < N_CLUSTERS; ++k) s1[wave][k][lane] = a[k];
    if (lane == 0) {
#pragma unroll
      for (int k = 0; k < N_CLUSTERS; ++k) scnt[wave][k] = cn[k];
    }
    __syncthreads();
    const float* fs1 = smem;
    for (int i = t; i < N_CLUSTERS * N_D; i += 256) {
      S1p[blockIdx.x * 640 + i] =
          fs1[i] + fs1[640 + i] + fs1[1280 + i] + fs1[1920 + i];
    }
    if (t < N_CLUSTERS) {
      cntp[blockIdx.x * N_CLUSTERS + t] =
          scnt[0][t] + scnt[1][t] + scnt[2][t] + scnt[3][t];
    }
  } else {
    // ---- w2p: transpose + split-plane bf16 hi/lo ----
    float (*tile)[65] = (float (*)[65])smem;   // +1 pad: conflict-free
    int blk = blockIdx.x - K1B;
    int c0 = blk * 64;
    int cl_ = t & 63;
    int r0 = t >> 6;
    bool okr = (c0 + cl_) < N_ITEMS;
#pragma unroll
    for (int rr = 0; rr < 16; ++rr) {
      int r = rr * 4 + r0;
      tile[cl_][r] = okr ? W2[(size_t)r * N_ITEMS + c0 + cl_] : 0.f;
    }
    __syncthreads();
#pragma unroll
    for (int itw = 0; itw < 8; ++itw) {
      int task = itw * 256 + t;                // 2048 tasks: (col, dpair)
      int c_l = task >> 5, dp = task & 31;
      int c = c0 + c_l;
      if (c < N_ITEMS) {
        float v0 = tile[c_l][dp * 2], v1 = tile[c_l][dp * 2 + 1];
        unsigned short h0 = bf16_rne(v0), h1 = bf16_rne(v1);
        unsigned short l0 = bf16_rne(v0 - bf16_f(h0));
        unsigned short l1 = bf16_rne(v1 - bf16_f(h1));
        ((unsigned*)W2Ph)[(size_t)c * 32 + dp] =
            (unsigned)h0 | ((unsigned)h1 << 16);
        ((unsigned*)W2Pl)[(size_t)c * 32 + dp] =
            (unsigned)l0 | ((unsigned)l1 << 16);
      }
    }
  }
}

// ---------------------------------------------------------------------------
// Kernel 1r (11 blocks):
//   block 0: cursor zero + parallel count reduce + segment bases + tinfo
//   blocks 1..10: S1g reduce, 64 cols each, 4 waves x 98 coalesced loads
// ---------------------------------------------------------------------------
__global__ __launch_bounds__(256) void k1r(
    const float* __restrict__ S1p, const float* __restrict__ cntp,
    float* __restrict__ S1g, float* __restrict__ cntF, int* __restrict__ meta,
    int* __restrict__ tinfo, int* __restrict__ cursor) {
  int t = threadIdx.x;
  if (blockIdx.x > 0) {                        // ---- S1g chunk reduce ----
    __shared__ float sgp[4][64];
    int wave = t >> 6, lane = t & 63;
    int col = (blockIdx.x - 1) * 64 + lane;
    float s = 0.f;
    const float* sp = S1p + col;
#pragma unroll 4
    for (int b = wave; b < K1B; b += 4) s += sp[b * 640];
    sgp[wave][lane] = s;
    __syncthreads();
    if (t < 64) {
      S1g[(blockIdx.x - 1) * 64 + t] =
          sgp[0][t] + sgp[1][t] + sgp[2][t] + sgp[3][t];
    }
    return;
  }
  __shared__ int baseS[11];
  __shared__ int cntI[N_CLUSTERS];
  __shared__ float part[16][N_CLUSTERS];
  if (t < 16) cursor[t] = 0;
  if (t < 160) {                               // coalesced count reduce
    int c = t % N_CLUSTERS, g = t / N_CLUSTERS;
    float s = 0.f;
    for (int b = g; b < K1B; b += 16) s += cntp[b * N_CLUSTERS + c];
    part[g][c] = s;
  }
  __syncthreads();
  if (t < N_CLUSTERS) {
    float s = 0.f;
#pragma unroll
    for (int g = 0; g < 16; ++g) s += part[g][t];
    cntF[t] = s;
    cntI[t] = (int)(s + 0.5f);
  }
  __syncthreads();
  if (t == 0) {
    int acc = 0;
    for (int c = 0; c < N_CLUSTERS; ++c) {
      baseS[c] = acc;
      acc += ((cntI[c] + 15) >> 4) << 4;       // 16-align each segment
    }
    baseS[10] = acc;
    for (int c = 0; c < 11; ++c) meta[c] = baseS[c];
    meta[11] = acc >> 4;                       // NT
  }
  __syncthreads();
  int NT = baseS[10] >> 4;
  for (int jt = t; jt < MAXT; jt += 256) {
    int c = 0, nv = 0;
    if (jt < NT) {
      int p0 = jt * 16;
      for (int k = 0; k < N_CLUSTERS; ++k)
        if (p0 >= baseS[k] && p0 < baseS[k + 1]) c = k;
      nv = min(16, cntI[c] - (p0 - baseS[c]));
      if (nv < 0) nv = 0;
    }
    tinfo[jt] = c | (nv << 8);
  }
}

// ---------------------------------------------------------------------------
// Kernel B (fused): blocks [0,391) = inverse perm + bucket zero;
// blocks [391,423) = A-fragment precompute (h = inp @ S1g, *log2e, RNE
// hi/lo split, MFMA A layout) -> hfrag, computed ONCE.
// ---------------------------------------------------------------------------
__global__ __launch_bounds__(256) void kB(
    const int* __restrict__ cl, const int* __restrict__ meta,
    int* __restrict__ cursor, int* __restrict__ inv,
    const float* __restrict__ inp, const float* __restrict__ S1g,
    short8* __restrict__ hfrag, float* __restrict__ bucket) {
  __shared__ int wn[4][N_CLUSTERS];
  __shared__ int bb[N_CLUSTERS];
  int t = threadIdx.x;
  if (blockIdx.x < 391) {
    int i = blockIdx.x * 256 + t;
    if (i < N_B * N_CLUSTERS) bucket[i] = 0.f;
    int wave = t >> 6, lane = t & 63;
    int c = (i < N_ITEMS) ? cl[i] : -1;
    unsigned long long m[N_CLUSTERS];
#pragma unroll
    for (int k = 0; k < N_CLUSTERS; ++k) {
      m[k] = __ballot(c == k);
      if (lane == 0) wn[wave][k] = __popcll(m[k]);
    }
    __syncthreads();
    if (t < N_CLUSTERS) {
      int tot = wn[0][t] + wn[1][t] + wn[2][t] + wn[3][t];
      bb[t] = tot ? atomicAdd(&cursor[t], tot) : 0;
    }
    __syncthreads();
    if (c >= 0) {
      int rank = 0;
#pragma unroll
      for (int k = 0; k < N_CLUSTERS; ++k)
        if (c == k) rank = __popcll(m[k] & ((1ull << lane) - 1ull));
      int wsum = 0;
      for (int w2 = 0; w2 < wave; ++w2) wsum += wn[w2][c];
      inv[meta[c] + bb[c] + wsum + rank] = i;
    }
  } else {
    int id = (blockIdx.x - 391) * 256 + t;     // 8192 (bx,rt,ks,lane) tuples
    int lane = id & 63;
    int ks = (id >> 6) & 1;
    int rt = (id >> 7) & 3;
    int bx = id >> 9;
    int row = bx * 64 + rt * 16 + (lane & 15);
    int d0 = ks * 32 + (lane >> 4) * 8;
    float hv[8];
#pragma unroll
    for (int j = 0; j < 8; ++j) hv[j] = 0.f;
#pragma unroll
    for (int c = 0; c < N_CLUSTERS; ++c) {
      float ic = inp[row * N_CLUSTERS + c];
      const float* sp = S1g + c * N_D + d0;
#pragma unroll
      for (int j = 0; j < 8; ++j) hv[j] += ic * sp[j];
    }
    short8 hi8, lo8;
#pragma unroll
    for (int j = 0; j < 8; ++j) {
      float x = hv[j] * 1.44269504088896340736f;   // fold log2(e) -> exp2
      unsigned short us = bf16_rne(x);
      hi8[j] = (short)us;
      lo8[j] = (short)bf16_rne(x - bf16_f(us));
    }
    int f0 = rt * 4 + ks * 2;
    hfrag[(bx * 16 + f0) * 64 + lane] = hi8;
    hfrag[(bx * 16 + f0 + 1) * 64 + lane] = lo8;
  }
}

// ---------------------------------------------------------------------------
// Kernel 3 (hot): register-resident A, split-plane B gather (loads ARE the
// MFMA operands), 1-deep register prefetch, readlane tinfo, atomic bucket.
// R5: launch_bounds(256, 4) — NOT 6. R4's (256,6) forced an 85-VGPR cap on
// a ~76+agpr working set -> spill to scratch (VGPR 40, FETCH 755 MB, 252us).
// At the natural ~76-90 VGPRs the HW already permits 5-6 blocks/CU; the
// occupancy lever is the GRID (16x96=1536=6/CU), not the register cap.
// ---------------------------------------------------------------------------
__global__ __launch_bounds__(256, 4) void k3_mfma(
    const unsigned short* __restrict__ W2Ph,
    const unsigned short* __restrict__ W2Pl,
    const short8* __restrict__ hfrag, const int* __restrict__ inv,
    const int* __restrict__ tinfo, float* __restrict__ bucket) {
  __shared__ int linv[4][288];                 // 17*16=272 used, 4.6 KB
  int t = threadIdx.x;
  int wave = t >> 6, lane = t & 63;
  int l15 = lane & 15, quad = lane >> 4;

  // bijective XCD swizzle: 1536 = 8 XCDs x 192; each XCD gets 12 complete
  // by-groups (all 16 bx of a by share B tiles -> L2 hits)
  int lid = blockIdx.y * 16 + blockIdx.x;
  int nid = (lid & 7) * 192 + (lid >> 3);
  int bx = nid & 15, by = nid >> 4;            // by 0..95

  int gw = by * 4 + wave;                      // 0..383
  int jt0 = (MAXT * gw) / NGW;
  int nt = (MAXT * (gw + 1)) / NGW - jt0;      // 16 or 17

  // A fragments -> registers (invariant across this wave's tiles)
  short8 fr[16];
  {
    const short8* hp = hfrag + bx * 1024 + lane;
#pragma unroll
    for (int f = 0; f < 16; ++f) fr[f] = hp[f * 64];
  }
  // tinfo slice -> lane registers (readlane broadcast later)
  int tiv = tinfo[jt0 + ((lane < nt) ? lane : nt - 1)];
  // stage this wave's col slice into LDS
  {
    const int* ip = inv + jt0 * 16;
    int n = nt * 16;
    for (int i = lane; i < n; i += 64) linv[wave][i] = ip[i];
  }
  __syncthreads();

  f32x4 acc[4];
#pragma unroll
  for (int r = 0; r < 4; ++r) acc[r] = (f32x4){0.f, 0.f, 0.f, 0.f};

  short8 xh0, xl0, xh1, xl1, yh0, yl0, yh1, yl1;
  int cc, nv, colN;
  {
    int c0 = inv[jt0 * 16 + l15];
    int o = c0 * 64 + quad * 8;
    xh0 = *(const short8*)(W2Ph + o);
    xh1 = *(const short8*)(W2Ph + o + 32);
    xl0 = *(const short8*)(W2Pl + o);
    xl1 = *(const short8*)(W2Pl + o + 32);
    colN = inv[jt0 * 16 + 16 + l15];           // tile 1 (nt >= 16 always)
    int ti = __builtin_amdgcn_readlane(tiv, 0);
    cc = ti & 255;
    nv = ti >> 8;
  }

#define K3_FLUSH()                                                            \
  {                                                                           \
    _Pragma("unroll") for (int rt = 0; rt < 4; ++rt) {                        \
      float e0 = acc[rt][0], e1 = acc[rt][1];                                 \
      float e2 = acc[rt][2], e3 = acc[rt][3];                                 \
      _Pragma("unroll") for (int mm = 1; mm < 16; mm <<= 1) {                 \
        e0 += __shfl_xor(e0, mm, 64);                                         \
        e1 += __shfl_xor(e1, mm, 64);                                         \
        e2 += __shfl_xor(e2, mm, 64);                                         \
        e3 += __shfl_xor(e3, mm, 64);                                         \
      }                                                                       \
      if (l15 == 0) {                                                         \
        int r = bx * 64 + rt * 16 + quad * 4;                                 \
        atomicAdd(&bucket[(r + 0) * N_CLUSTERS + cc], e0);                    \
        atomicAdd(&bucket[(r + 1) * N_CLUSTERS + cc], e1);                    \
        atomicAdd(&bucket[(r + 2) * N_CLUSTERS + cc], e2);                    \
        atomicAdd(&bucket[(r + 3) * N_CLUSTERS + cc], e3);                    \
      }                                                                       \
      acc[rt] = (f32x4){0.f, 0.f, 0.f, 0.f};                                  \
    }                                                                         \
  }

#define K3_PHASE(CH0, CL0, CH1, CL1, NH0, NL0, NH1, NL1)                      \
  {                                                                           \
    int tin = __builtin_amdgcn_readlane(tiv, (it + 1 < nt) ? it + 1 : nt - 1);\
    int ccn = tin & 255, nvn = tin >> 8;                                      \
    {                                                                         \
      int o = colN * 64 + quad * 8;            /* prefetch tile it+1 */       \
      NH0 = *(const short8*)(W2Ph + o);                                       \
      NH1 = *(const short8*)(W2Ph + o + 32);                                  \
      NL0 = *(const short8*)(W2Pl + o);                                       \
      NL1 = *(const short8*)(W2Pl + o + 32);                                  \
    }                                                                         \
    colN = linv[wave][((it + 2 < nt) ? it + 2 : nt - 1) * 16 + l15];          \
    f32x4 cr[4];                                                              \
    _Pragma("unroll") for (int rt = 0; rt < 4; ++rt) {                        \
      f32x4 c = {0.f, 0.f, 0.f, 0.f};                                         \
      c = MFMA(fr[rt * 4 + 0], CH0, c);                                       \
      c = MFMA(fr[rt * 4 + 0], CL0, c);                                       \
      c = MFMA(fr[rt * 4 + 1], CH0, c);                                       \
      c = MFMA(fr[rt * 4 + 2], CH1, c);                                       \
      c = MFMA(fr[rt * 4 + 2], CL1, c);                                       \
      c = MFMA(fr[rt * 4 + 3], CH1, c);                                       \
      cr[rt] = c;                                                             \
    }                                                                         \
    if (nv == 16) {                                                           \
      _Pragma("unroll") for (int rt = 0; rt < 4; ++rt) {                      \
        acc[rt][0] += EXP2F(cr[rt][0]);                                       \
        acc[rt][1] += EXP2F(cr[rt][1]);                                       \
        acc[rt][2] += EXP2F(cr[rt][2]);                                       \
        acc[rt][3] += EXP2F(cr[rt][3]);                                       \
      }                                                                       \
    } else {                                                                  \
      _Pragma("unroll") for (int rt = 0; rt < 4; ++rt) {                      \
        acc[rt][0] += (l15 < nv) ? EXP2F(cr[rt][0]) : 0.f;                    \
        acc[rt][1] += (l15 < nv) ? EXP2F(cr[rt][1]) : 0.f;                    \
        acc[rt][2] += (l15 < nv) ? EXP2F(cr[rt][2]) : 0.f;                    \
        acc[rt][3] += (l15 < nv) ? EXP2F(cr[rt][3]) : 0.f;                    \
      }                                                                       \
    }                                                                         \
    if (it == nt - 1 || ccn != cc) K3_FLUSH();                                \
    cc = ccn;                                                                 \
    nv = nvn;                                                                 \
    ++it;                                                                     \
    if (it == nt) break;                                                      \
  }

  int it = 0;
  while (true) {
    K3_PHASE(xh0, xl0, xh1, xl1, yh0, yl0, yh1, yl1)
    K3_PHASE(yh0, yl0, yh1, yl1, xh0, xl0, xh1, xl1)
  }
#undef K3_PHASE
#undef K3_FLUSH
}

// ---------------------------------------------------------------------------
// Kernel 4: normalize (softmax denom = per-row sum over clusters), /counts.
// ---------------------------------------------------------------------------
__global__ __launch_bounds__(320) void k4_fin(
    const float* __restrict__ bucket, const float* __restrict__ cntF,
    float* __restrict__ out) {
  __shared__ float bl[32][N_CLUSTERS];
  int t = threadIdx.x;                         // 0..319
  int r = t / N_CLUSTERS, c = t % N_CLUSTERS;
  int row = blockIdx.x * 32 + r;
  float s = bucket[row * N_CLUSTERS + c];
  bl[r][c] = s;
  __syncthreads();
  float tot = 0.f;
#pragma unroll
  for (int k = 0; k < N_CLUSTERS; ++k) tot += bl[r][k];
  out[row * N_CLUSTERS + c] = s / (tot * fmaxf(cntF[c], 1.f));
}

// ---------------------------------------------------------------------------
// Workspace layout (4-byte units), total 27.7 MB:
//   [0,640) S1g | [640,656) cntF | [656,672) meta | [672,688) cursor
//   [1024,7296) tinfo = cluster|(nv<<8) | [16384,116736) inv
//   [131072,196608) hfrag (256 KB, MFMA A layout, log2e folded)
//   [262144,3463168) W2Ph (bf16 hi plane, item-major)
//   [3463168,6664192) W2Pl (bf16 lo plane)
//   [6664192,6915072) S1p | [6915072,6918992) cntp
//   [6918992,6929232) bucket (atomic accum; zeroed in kB)
// No memset: inv zeroed by kA, cursor by k1r, bucket by kB.
// ---------------------------------------------------------------------------
extern "C" void kernel_launch(void* const* d_in, const int* in_sizes, int n_in,
                              void* d_out, int out_size, void* d_ws, size_t ws_size,
                              hipStream_t stream) {
  const float* input = (const float*)d_in[0];   // (1024, 10) f32
  const int* cl      = (const int*)d_in[1];     // (100000,) i32
  const float* W1    = (const float*)d_in[2];   // (100000, 64) f32
  const float* W2    = (const float*)d_in[3];   // (64, 100000) f32
  float* out = (float*)d_out;
  float* ws = (float*)d_ws;

  float* S1g            = ws;
  float* cntF           = ws + 640;
  int*   meta           = (int*)(ws + 656);
  int*   cursor         = (int*)(ws + 672);
  int*   tinfo          = (int*)(ws + 1024);
  int*   inv            = (int*)(ws + 16384);
  short8* hfrag         = (short8*)(ws + 131072);
  unsigned short* W2Ph  = (unsigned short*)(ws + 262144);
  unsigned short* W2Pl  = (unsigned short*)(ws + 3463168);
  float* S1p            = ws + 6664192;
  float* cntp           = ws + 6915072;
  float* bucket         = ws + 6918992;

  kA<<<K1B + W2PB, 256, 0, stream>>>(cl, W1, W2, S1p, cntp, inv, W2Ph, W2Pl);
  k1r<<<11, 256, 0, stream>>>(S1p, cntp, S1g, cntF, meta, tinfo, cursor);
  kB<<<391 + 32, 256, 0, stream>>>(cl, meta, cursor, inv, input, S1g, hfrag,
                                   bucket);
  dim3 g3(16, K3BY);                            // 1536 blocks = 6/CU
  k3_mfma<<<g3, 256, 0, stream>>>(W2Ph, W2Pl, hfrag, inv, tinfo, bucket);
  k4_fin<<<32, 320, 0, stream>>>(bucket, cntF, out);
}

// Round 6
// 225.969 us; speedup vs baseline: 1.6418x; 1.0784x over previous
//
#include <hip/hip_runtime.h>
#include <hip/hip_bf16.h>

#define N_B 1024
#define N_ITEMS 100000
#define N_CLUSTERS 10
#define N_D 64
#define MAXT 6272            // padded tile capacity; NT <= 6260 always
#define K1B 392              // segsum blocks: 392*4 waves*64 rows = 100352
#define W2PB 1563            // w2p blocks: 1563*64 = 100032 cols
#define K3BX 32              // 32 output rows per wave (was 64) -> small regs
#define K3BY 48
#define NGW 192              // 48 by * 4 waves; tiles/wave = 6272/192 = 32.67

typedef __attribute__((ext_vector_type(8))) short short8;
typedef __attribute__((ext_vector_type(4))) float f32x4;

#if defined(__has_builtin)
#if __has_builtin(__builtin_amdgcn_exp2f)
#define EXP2F(x) __builtin_amdgcn_exp2f(x)
#endif
#endif
#ifndef EXP2F
#define EXP2F(x) exp2f(x)
#endif

#define MFMA(a, b, c) __builtin_amdgcn_mfma_f32_16x16x32_bf16(a, b, c, 0, 0, 0)

// bf16 RNE split helpers (bit-level; sign-safe)
__device__ __forceinline__ unsigned short bf16_rne(float x) {
  unsigned u = __float_as_uint(x);
  u += 0x7FFFu + ((u >> 16) & 1u);
  return (unsigned short)(u >> 16);
}
__device__ __forceinline__ float bf16_f(unsigned short b) {
  return __uint_as_float(((unsigned)b) << 16);
}

// ---------------------------------------------------------------------------
// Kernel A (fused): blocks [0,392) = per-block partial S1/counts + inv zero;
// blocks [392,1955) = W2 transpose into SPLIT bf16 hi/lo planes (item-major).
// ---------------------------------------------------------------------------
__global__ __launch_bounds__(256) void kA(
    const int* __restrict__ cl, const float* __restrict__ W1,
    const float* __restrict__ W2, float* __restrict__ S1p,
    float* __restrict__ cntp, int* __restrict__ inv,
    unsigned short* __restrict__ W2Ph, unsigned short* __restrict__ W2Pl) {
  __shared__ float smem[64 * 65];              // 16.6 KB; segsum uses 2600
  int t = threadIdx.x;
  if (blockIdx.x < K1B) {
    // ---- segsum ----
    float (*s1)[N_CLUSTERS][N_D] = (float (*)[N_CLUSTERS][N_D])smem;
    float (*scnt)[N_CLUSTERS] =
        (float (*)[N_CLUSTERS])(smem + 4 * N_CLUSTERS * N_D);
    int wave = t >> 6, lane = t & 63;

    inv[blockIdx.x * 256 + t] = 0;             // zero all MAXT*16 slots

    float a[N_CLUSTERS], cn[N_CLUSTERS];
#pragma unroll
    for (int k = 0; k < N_CLUSTERS; ++k) { a[k] = 0.f; cn[k] = 0.f; }

    int gw = blockIdx.x * 4 + wave;
    int r0 = gw * 64;
#pragma unroll 1
    for (int b = 0; b < 8; ++b) {
      int i0 = r0 + b * 8;
      float w[8];
      int c[8];
      if (i0 + 8 <= N_ITEMS) {
#pragma unroll
        for (int j = 0; j < 8; ++j) {
          c[j] = cl[i0 + j];                   // wave-uniform -> s_load
          w[j] = W1[(size_t)(i0 + j) * N_D + lane];
        }
      } else {
#pragma unroll
        for (int j = 0; j < 8; ++j) {
          int i = i0 + j;
          bool ok = i < N_ITEMS;
          c[j] = ok ? cl[i] : -1;
          w[j] = ok ? W1[(size_t)i * N_D + lane] : 0.f;
        }
      }
#pragma unroll
      for (int j = 0; j < 8; ++j)
#pragma unroll
        for (int k = 0; k < N_CLUSTERS; ++k) {
          bool m = (c[j] == k);
          a[k] += m ? w[j] : 0.f;
          cn[k] += m ? 1.f : 0.f;
        }
    }
#pragma unroll
    for (int k = 0; k < N_CLUSTERS; ++k) s1[wave][k][lane] = a[k];
    if (lane == 0) {
#pragma unroll
      for (int k = 0; k < N_CLUSTERS; ++k) scnt[wave][k] = cn[k];
    }
    __syncthreads();
    const float* fs1 = smem;
    for (int i = t; i < N_CLUSTERS * N_D; i += 256) {
      S1p[blockIdx.x * 640 + i] =
          fs1[i] + fs1[640 + i] + fs1[1280 + i] + fs1[1920 + i];
    }
    if (t < N_CLUSTERS) {
      cntp[blockIdx.x * N_CLUSTERS + t] =
          scnt[0][t] + scnt[1][t] + scnt[2][t] + scnt[3][t];
    }
  } else {
    // ---- w2p: transpose + split-plane bf16 hi/lo ----
    float (*tile)[65] = (float (*)[65])smem;   // +1 pad: conflict-free
    int blk = blockIdx.x - K1B;
    int c0 = blk * 64;
    int cl_ = t & 63;
    int r0 = t >> 6;
    bool okr = (c0 + cl_) < N_ITEMS;
#pragma unroll
    for (int rr = 0; rr < 16; ++rr) {
      int r = rr * 4 + r0;
      tile[cl_][r] = okr ? W2[(size_t)r * N_ITEMS + c0 + cl_] : 0.f;
    }
    __syncthreads();
#pragma unroll
    for (int itw = 0; itw < 8; ++itw) {
      int task = itw * 256 + t;                // 2048 tasks: (col, dpair)
      int c_l = task >> 5, dp = task & 31;
      int c = c0 + c_l;
      if (c < N_ITEMS) {
        float v0 = tile[c_l][dp * 2], v1 = tile[c_l][dp * 2 + 1];
        unsigned short h0 = bf16_rne(v0), h1 = bf16_rne(v1);
        unsigned short l0 = bf16_rne(v0 - bf16_f(h0));
        unsigned short l1 = bf16_rne(v1 - bf16_f(h1));
        ((unsigned*)W2Ph)[(size_t)c * 32 + dp] =
            (unsigned)h0 | ((unsigned)h1 << 16);
        ((unsigned*)W2Pl)[(size_t)c * 32 + dp] =
            (unsigned)l0 | ((unsigned)l1 << 16);
      }
    }
  }
}

// ---------------------------------------------------------------------------
// Kernel 1r (11 blocks):
//   block 0: cursor zero + parallel count reduce + segment bases + tinfo
//   blocks 1..10: S1g reduce, 64 cols each, 4 waves x 98 coalesced loads
// ---------------------------------------------------------------------------
__global__ __launch_bounds__(256) void k1r(
    const float* __restrict__ S1p, const float* __restrict__ cntp,
    float* __restrict__ S1g, float* __restrict__ cntF, int* __restrict__ meta,
    int* __restrict__ tinfo, int* __restrict__ cursor) {
  int t = threadIdx.x;
  if (blockIdx.x > 0) {                        // ---- S1g chunk reduce ----
    __shared__ float sgp[4][64];
    int wave = t >> 6, lane = t & 63;
    int col = (blockIdx.x - 1) * 64 + lane;
    float s = 0.f;
    const float* sp = S1p + col;
#pragma unroll 4
    for (int b = wave; b < K1B; b += 4) s += sp[b * 640];
    sgp[wave][lane] = s;
    __syncthreads();
    if (t < 64) {
      S1g[(blockIdx.x - 1) * 64 + t] =
          sgp[0][t] + sgp[1][t] + sgp[2][t] + sgp[3][t];
    }
    return;
  }
  __shared__ int baseS[11];
  __shared__ int cntI[N_CLUSTERS];
  __shared__ float part[16][N_CLUSTERS];
  if (t < 16) cursor[t] = 0;
  if (t < 160) {                               // coalesced count reduce
    int c = t % N_CLUSTERS, g = t / N_CLUSTERS;
    float s = 0.f;
    for (int b = g; b < K1B; b += 16) s += cntp[b * N_CLUSTERS + c];
    part[g][c] = s;
  }
  __syncthreads();
  if (t < N_CLUSTERS) {
    float s = 0.f;
#pragma unroll
    for (int g = 0; g < 16; ++g) s += part[g][t];
    cntF[t] = s;
    cntI[t] = (int)(s + 0.5f);
  }
  __syncthreads();
  if (t == 0) {
    int acc = 0;
    for (int c = 0; c < N_CLUSTERS; ++c) {
      baseS[c] = acc;
      acc += ((cntI[c] + 15) >> 4) << 4;       // 16-align each segment
    }
    baseS[10] = acc;
    for (int c = 0; c < 11; ++c) meta[c] = baseS[c];
    meta[11] = acc >> 4;                       // NT
  }
  __syncthreads();
  int NT = baseS[10] >> 4;
  for (int jt = t; jt < MAXT; jt += 256) {
    int c = 0, nv = 0;
    if (jt < NT) {
      int p0 = jt * 16;
      for (int k = 0; k < N_CLUSTERS; ++k)
        if (p0 >= baseS[k] && p0 < baseS[k + 1]) c = k;
      nv = min(16, cntI[c] - (p0 - baseS[c]));
      if (nv < 0) nv = 0;
    }
    tinfo[jt] = c | (nv << 8);
  }
}

// ---------------------------------------------------------------------------
// Kernel B (fused): blocks [0,391) = inverse perm + bucket zero;
// blocks [391,423) = A-fragment precompute for 32-ROW tiles: 32 bx x 8
// frags x 64 lanes (h = inp @ S1g, *log2e, RNE hi/lo split, MFMA A layout).
// ---------------------------------------------------------------------------
__global__ __launch_bounds__(256) void kB(
    const int* __restrict__ cl, const int* __restrict__ meta,
    int* __restrict__ cursor, int* __restrict__ inv,
    const float* __restrict__ inp, const float* __restrict__ S1g,
    short8* __restrict__ hfrag, float* __restrict__ bucket) {
  __shared__ int wn[4][N_CLUSTERS];
  __shared__ int bb[N_CLUSTERS];
  int t = threadIdx.x;
  if (blockIdx.x < 391) {
    int i = blockIdx.x * 256 + t;
    if (i < N_B * N_CLUSTERS) bucket[i] = 0.f;
    int wave = t >> 6, lane = t & 63;
    int c = (i < N_ITEMS) ? cl[i] : -1;
    unsigned long long m[N_CLUSTERS];
#pragma unroll
    for (int k = 0; k < N_CLUSTERS; ++k) {
      m[k] = __ballot(c == k);
      if (lane == 0) wn[wave][k] = __popcll(m[k]);
    }
    __syncthreads();
    if (t < N_CLUSTERS) {
      int tot = wn[0][t] + wn[1][t] + wn[2][t] + wn[3][t];
      bb[t] = tot ? atomicAdd(&cursor[t], tot) : 0;
    }
    __syncthreads();
    if (c >= 0) {
      int rank = 0;
#pragma unroll
      for (int k = 0; k < N_CLUSTERS; ++k)
        if (c == k) rank = __popcll(m[k] & ((1ull << lane) - 1ull));
      int wsum = 0;
      for (int w2 = 0; w2 < wave; ++w2) wsum += wn[w2][c];
      inv[meta[c] + bb[c] + wsum + rank] = i;
    }
  } else {
    int id = (blockIdx.x - 391) * 256 + t;     // 8192 (bx,rt,ks,lane) tuples
    int lane = id & 63;
    int ks = (id >> 6) & 1;
    int rt = (id >> 7) & 1;                    // 2 row-tiles of 16 per bx
    int bx = id >> 8;                          // 0..31
    int row = bx * K3BX + rt * 16 + (lane & 15);
    int d0 = ks * 32 + (lane >> 4) * 8;
    float hv[8];
#pragma unroll
    for (int j = 0; j < 8; ++j) hv[j] = 0.f;
#pragma unroll
    for (int c = 0; c < N_CLUSTERS; ++c) {
      float ic = inp[row * N_CLUSTERS + c];
      const float* sp = S1g + c * N_D + d0;
#pragma unroll
      for (int j = 0; j < 8; ++j) hv[j] += ic * sp[j];
    }
    short8 hi8, lo8;
#pragma unroll
    for (int j = 0; j < 8; ++j) {
      float x = hv[j] * 1.44269504088896340736f;   // fold log2(e) -> exp2
      unsigned short us = bf16_rne(x);
      hi8[j] = (short)us;
      lo8[j] = (short)bf16_rne(x - bf16_f(us));
    }
    int f0 = rt * 4 + ks * 2;                  // 0,2,4,6
    hfrag[(bx * 8 + f0) * 64 + lane] = hi8;
    hfrag[(bx * 8 + f0 + 1) * 64 + lane] = lo8;
  }
}

// ---------------------------------------------------------------------------
// Kernel 3 (hot). R6: the register working set IS the occupancy limiter
// (R3: ~170 unified regs -> 3 waves/SIMD; R4/R5 proved launch-bounds caps
// just cause spills). Shrink it: 32-row wave-tiles -> fr[8] (32 regs),
// acc[2], exp merged into the MFMA loop (no cr[] array). ~105-115 regs
// -> 4 waves/SIMD under (256,4) WITHOUT spill. B-gather L2 traffic
// doubles (~410 MB, ~12us at L2 BW — not binding).
// ---------------------------------------------------------------------------
__global__ __launch_bounds__(256, 4) void k3_mfma(
    const unsigned short* __restrict__ W2Ph,
    const unsigned short* __restrict__ W2Pl,
    const short8* __restrict__ hfrag, const int* __restrict__ inv,
    const int* __restrict__ tinfo, float* __restrict__ bucket) {
  __shared__ int linv[4][544];                 // 33*16=528 used, 8.7 KB
  int t = threadIdx.x;
  int wave = t >> 6, lane = t & 63;
  int l15 = lane & 15, quad = lane >> 4;

  // bijective XCD swizzle: 1536 = 8 XCDs x 192; consecutive nids on one XCD
  // walk bx within a by-group (shared B cols -> L2 hits)
  int lid = blockIdx.y * K3BX + blockIdx.x;
  int nid = (lid & 7) * 192 + (lid >> 3);
  int bx = nid & 31, by = nid >> 5;            // bx 0..31, by 0..47

  int gw = by * 4 + wave;                      // 0..191
  int jt0 = (MAXT * gw) / NGW;
  int nt = (MAXT * (gw + 1)) / NGW - jt0;      // 32 or 33

  // A fragments -> registers (invariant across this wave's tiles)
  short8 fr[8];
  {
    const short8* hp = hfrag + bx * 512 + lane;
#pragma unroll
    for (int f = 0; f < 8; ++f) fr[f] = hp[f * 64];
  }
  // tinfo slice -> lane registers (readlane broadcast later)
  int tiv = tinfo[jt0 + ((lane < nt) ? lane : nt - 1)];
  // stage this wave's col slice into LDS
  {
    const int* ip = inv + jt0 * 16;
    int n = nt * 16;
    for (int i = lane; i < n; i += 64) linv[wave][i] = ip[i];
  }
  __syncthreads();

  f32x4 acc[2];
#pragma unroll
  for (int r = 0; r < 2; ++r) acc[r] = (f32x4){0.f, 0.f, 0.f, 0.f};

  short8 xh0, xl0, xh1, xl1, yh0, yl0, yh1, yl1;
  int cc, nv, colN;
  {
    int c0 = inv[jt0 * 16 + l15];
    int o = c0 * 64 + quad * 8;
    xh0 = *(const short8*)(W2Ph + o);
    xh1 = *(const short8*)(W2Ph + o + 32);
    xl0 = *(const short8*)(W2Pl + o);
    xl1 = *(const short8*)(W2Pl + o + 32);
    colN = inv[jt0 * 16 + 16 + l15];           // tile 1 (nt >= 32 always)
    int ti = __builtin_amdgcn_readlane(tiv, 0);
    cc = ti & 255;
    nv = ti >> 8;
  }

#define K3_FLUSH()                                                            \
  {                                                                           \
    _Pragma("unroll") for (int rt = 0; rt < 2; ++rt) {                        \
      float e0 = acc[rt][0], e1 = acc[rt][1];                                 \
      float e2 = acc[rt][2], e3 = acc[rt][3];                                 \
      _Pragma("unroll") for (int mm = 1; mm < 16; mm <<= 1) {                 \
        e0 += __shfl_xor(e0, mm, 64);                                         \
        e1 += __shfl_xor(e1, mm, 64);                                         \
        e2 += __shfl_xor(e2, mm, 64);                                         \
        e3 += __shfl_xor(e3, mm, 64);                                         \
      }                                                                       \
      if (l15 == 0) {                                                         \
        int r = bx * K3BX + rt * 16 + quad * 4;                               \
        atomicAdd(&bucket[(r + 0) * N_CLUSTERS + cc], e0);                    \
        atomicAdd(&bucket[(r + 1) * N_CLUSTERS + cc], e1);                    \
        atomicAdd(&bucket[(r + 2) * N_CLUSTERS + cc], e2);                    \
        atomicAdd(&bucket[(r + 3) * N_CLUSTERS + cc], e3);                    \
      }                                                                       \
      acc[rt] = (f32x4){0.f, 0.f, 0.f, 0.f};                                  \
    }                                                                         \
  }

#define K3_PHASE(CH0, CL0, CH1, CL1, NH0, NL0, NH1, NL1)                      \
  {                                                                           \
    int tin = __builtin_amdgcn_readlane(tiv, (it + 1 < nt) ? it + 1 : nt - 1);\
    int ccn = tin & 255, nvn = tin >> 8;                                      \
    {                                                                         \
      int o = colN * 64 + quad * 8;            /* prefetch tile it+1 */       \
      NH0 = *(const short8*)(W2Ph + o);                                       \
      NH1 = *(const short8*)(W2Ph + o + 32);                                  \
      NL0 = *(const short8*)(W2Pl + o);                                       \
      NL1 = *(const short8*)(W2Pl + o + 32);                                  \
    }                                                                         \
    colN = linv[wave][((it + 2 < nt) ? it + 2 : nt - 1) * 16 + l15];          \
    _Pragma("unroll") for (int rt = 0; rt < 2; ++rt) {                        \
      f32x4 c = {0.f, 0.f, 0.f, 0.f};                                         \
      c = MFMA(fr[rt * 4 + 0], CH0, c);                                       \
      c = MFMA(fr[rt * 4 + 0], CL0, c);                                       \
      c = MFMA(fr[rt * 4 + 1], CH0, c);                                       \
      c = MFMA(fr[rt * 4 + 2], CH1, c);                                       \
      c = MFMA(fr[rt * 4 + 2], CL1, c);                                       \
      c = MFMA(fr[rt * 4 + 3], CH1, c);                                       \
      if (nv == 16) {                                                         \
        acc[rt][0] += EXP2F(c[0]);                                            \
        acc[rt][1] += EXP2F(c[1]);                                            \
        acc[rt][2] += EXP2F(c[2]);                                            \
        acc[rt][3] += EXP2F(c[3]);                                            \
      } else {                                                                \
        acc[rt][0] += (l15 < nv) ? EXP2F(c[0]) : 0.f;                         \
        acc[rt][1] += (l15 < nv) ? EXP2F(c[1]) : 0.f;                         \
        acc[rt][2] += (l15 < nv) ? EXP2F(c[2]) : 0.f;                         \
        acc[rt][3] += (l15 < nv) ? EXP2F(c[3]) : 0.f;                         \
      }                                                                       \
    }                                                                         \
    if (it == nt - 1 || ccn != cc) K3_FLUSH();                                \
    cc = ccn;                                                                 \
    nv = nvn;                                                                 \
    ++it;                                                                     \
    if (it == nt) break;                                                      \
  }

  int it = 0;
  while (true) {
    K3_PHASE(xh0, xl0, xh1, xl1, yh0, yl0, yh1, yl1)
    K3_PHASE(yh0, yl0, yh1, yl1, xh0, xl0, xh1, xl1)
  }
#undef K3_PHASE
#undef K3_FLUSH
}

// ---------------------------------------------------------------------------
// Kernel 4: normalize (softmax denom = per-row sum over clusters), /counts.
// ---------------------------------------------------------------------------
__global__ __launch_bounds__(320) void k4_fin(
    const float* __restrict__ bucket, const float* __restrict__ cntF,
    float* __restrict__ out) {
  __shared__ float bl[32][N_CLUSTERS];
  int t = threadIdx.x;                         // 0..319
  int r = t / N_CLUSTERS, c = t % N_CLUSTERS;
  int row = blockIdx.x * 32 + r;
  float s = bucket[row * N_CLUSTERS + c];
  bl[r][c] = s;
  __syncthreads();
  float tot = 0.f;
#pragma unroll
  for (int k = 0; k < N_CLUSTERS; ++k) tot += bl[r][k];
  out[row * N_CLUSTERS + c] = s / (tot * fmaxf(cntF[c], 1.f));
}

// ---------------------------------------------------------------------------
// Workspace layout (4-byte units), total 27.7 MB:
//   [0,640) S1g | [640,656) cntF | [656,672) meta | [672,688) cursor
//   [1024,7296) tinfo = cluster|(nv<<8) | [16384,116736) inv
//   [131072,196608) hfrag (256 KB, MFMA A layout, log2e folded)
//   [262144,3463168) W2Ph (bf16 hi plane, item-major)
//   [3463168,6664192) W2Pl (bf16 lo plane)
//   [6664192,6915072) S1p | [6915072,6918992) cntp
//   [6918992,6929232) bucket (atomic accum; zeroed in kB)
// No memset: inv zeroed by kA, cursor by k1r, bucket by kB.
// ---------------------------------------------------------------------------
extern "C" void kernel_launch(void* const* d_in, const int* in_sizes, int n_in,
                              void* d_out, int out_size, void* d_ws, size_t ws_size,
                              hipStream_t stream) {
  const float* input = (const float*)d_in[0];   // (1024, 10) f32
  const int* cl      = (const int*)d_in[1];     // (100000,) i32
  const float* W1    = (const float*)d_in[2];   // (100000, 64) f32
  const float* W2    = (const float*)d_in[3];   // (64, 100000) f32
  float* out = (float*)d_out;
  float* ws = (float*)d_ws;

  float* S1g            = ws;
  float* cntF           = ws + 640;
  int*   meta           = (int*)(ws + 656);
  int*   cursor         = (int*)(ws + 672);
  int*   tinfo          = (int*)(ws + 1024);
  int*   inv            = (int*)(ws + 16384);
  short8* hfrag         = (short8*)(ws + 131072);
  unsigned short* W2Ph  = (unsigned short*)(ws + 262144);
  unsigned short* W2Pl  = (unsigned short*)(ws + 3463168);
  float* S1p            = ws + 6664192;
  float* cntp           = ws + 6915072;
  float* bucket         = ws + 6918992;

  kA<<<K1B + W2PB, 256, 0, stream>>>(cl, W1, W2, S1p, cntp, inv, W2Ph, W2Pl);
  k1r<<<11, 256, 0, stream>>>(S1p, cntp, S1g, cntF, meta, tinfo, cursor);
  kB<<<391 + 32, 256, 0, stream>>>(cl, meta, cursor, inv, input, S1g, hfrag,
                                   bucket);
  dim3 g3(K3BX, K3BY);                          // 32 x 48 = 1536 blocks
  k3_mfma<<<g3, 256, 0, stream>>>(W2Ph, W2Pl, hfrag, inv, tinfo, bucket);
  k4_fin<<<32, 320, 0, stream>>>(bucket, cntF, out);
}

// Round 8
// 179.241 us; speedup vs baseline: 2.0698x; 1.2607x over previous
//
#include <hip/hip_runtime.h>
#include <hip/hip_bf16.h>

#define N_B 1024
#define N_ITEMS 100000
#define N_CLUSTERS 10
#define N_D 64
#define MAXT 6272            // padded tile capacity; NT <= 6260 always
#define K1B 392              // segsum blocks: 392*4 waves*64 rows = 100352
#define W2PB 1563            // w2p blocks: 1563*64 = 100032 cols
#define K3BY 48              // k3 grid: 16 x 48 = 768 = 3 blocks/CU
#define NGW 192              // 48 by * 4 waves; tiles/wave = 6272/192 = 32.67

typedef __attribute__((ext_vector_type(8))) short short8;
typedef __attribute__((ext_vector_type(4))) float f32x4;

#if defined(__has_builtin)
#if __has_builtin(__builtin_amdgcn_exp2f)
#define EXP2F(x) __builtin_amdgcn_exp2f(x)
#endif
#endif
#ifndef EXP2F
#define EXP2F(x) exp2f(x)
#endif

#define MFMA(a, b, c) __builtin_amdgcn_mfma_f32_16x16x32_bf16(a, b, c, 0, 0, 0)

// bf16 RNE split helpers (bit-level; sign-safe)
__device__ __forceinline__ unsigned short bf16_rne(float x) {
  unsigned u = __float_as_uint(x);
  u += 0x7FFFu + ((u >> 16) & 1u);
  return (unsigned short)(u >> 16);
}
__device__ __forceinline__ float bf16_f(unsigned short b) {
  return __uint_as_float(((unsigned)b) << 16);
}

// ---------------------------------------------------------------------------
// Kernel A (fused): blocks [0,392) = per-block partial S1/counts + inv zero;
// blocks [392,1955) = W2 transpose into SPLIT bf16 hi/lo planes (item-major).
// ---------------------------------------------------------------------------
__global__ __launch_bounds__(256) void kA(
    const int* __restrict__ cl, const float* __restrict__ W1,
    const float* __restrict__ W2, float* __restrict__ S1p,
    float* __restrict__ cntp, int* __restrict__ inv,
    unsigned short* __restrict__ W2Ph, unsigned short* __restrict__ W2Pl) {
  __shared__ float smem[64 * 65];              // 16.6 KB; segsum uses 2600
  int t = threadIdx.x;
  if (blockIdx.x < K1B) {
    // ---- segsum ----
    float (*s1)[N_CLUSTERS][N_D] = (float (*)[N_CLUSTERS][N_D])smem;
    float (*scnt)[N_CLUSTERS] =
        (float (*)[N_CLUSTERS])(smem + 4 * N_CLUSTERS * N_D);
    int wave = t >> 6, lane = t & 63;

    inv[blockIdx.x * 256 + t] = 0;             // zero all MAXT*16 slots

    float a[N_CLUSTERS], cn[N_CLUSTERS];
#pragma unroll
    for (int k = 0; k < N_CLUSTERS; ++k) { a[k] = 0.f; cn[k] = 0.f; }

    int gw = blockIdx.x * 4 + wave;
    int r0 = gw * 64;
#pragma unroll 1
    for (int b = 0; b < 8; ++b) {
      int i0 = r0 + b * 8;
      float w[8];
      int c[8];
      if (i0 + 8 <= N_ITEMS) {
#pragma unroll
        for (int j = 0; j < 8; ++j) {
          c[j] = cl[i0 + j];                   // wave-uniform -> s_load
          w[j] = W1[(size_t)(i0 + j) * N_D + lane];
        }
      } else {
#pragma unroll
        for (int j = 0; j < 8; ++j) {
          int i = i0 + j;
          bool ok = i < N_ITEMS;
          c[j] = ok ? cl[i] : -1;
          w[j] = ok ? W1[(size_t)i * N_D + lane] : 0.f;
        }
      }
#pragma unroll
      for (int j = 0; j < 8; ++j)
#pragma unroll
        for (int k = 0; k < N_CLUSTERS; ++k) {
          bool m = (c[j] == k);
          a[k] += m ? w[j] : 0.f;
          cn[k] += m ? 1.f : 0.f;
        }
    }
#pragma unroll
    for (int k = 0; k < N_CLUSTERS; ++k) s1[wave][k][lane] = a[k];
    if (lane == 0) {
#pragma unroll
      for (int k = 0; k < N_CLUSTERS; ++k) scnt[wave][k] = cn[k];
    }
    __syncthreads();
    const float* fs1 = smem;
    for (int i = t; i < N_CLUSTERS * N_D; i += 256) {
      S1p[blockIdx.x * 640 + i] =
          fs1[i] + fs1[640 + i] + fs1[1280 + i] + fs1[1920 + i];
    }
    if (t < N_CLUSTERS) {
      cntp[blockIdx.x * N_CLUSTERS + t] =
          scnt[0][t] + scnt[1][t] + scnt[2][t] + scnt[3][t];
    }
  } else {
    // ---- w2p: transpose + split-plane bf16 hi/lo ----
    float (*tile)[65] = (float (*)[65])smem;   // +1 pad: conflict-free
    int blk = blockIdx.x - K1B;
    int c0 = blk * 64;
    int cl_ = t & 63;
    int r0 = t >> 6;
    bool okr = (c0 + cl_) < N_ITEMS;
#pragma unroll
    for (int rr = 0; rr < 16; ++rr) {
      int r = rr * 4 + r0;
      tile[cl_][r] = okr ? W2[(size_t)r * N_ITEMS + c0 + cl_] : 0.f;
    }
    __syncthreads();
#pragma unroll
    for (int itw = 0; itw < 8; ++itw) {
      int task = itw * 256 + t;                // 2048 tasks: (col, dpair)
      int c_l = task >> 5, dp = task & 31;
      int c = c0 + c_l;
      if (c < N_ITEMS) {
        float v0 = tile[c_l][dp * 2], v1 = tile[c_l][dp * 2 + 1];
        unsigned short h0 = bf16_rne(v0), h1 = bf16_rne(v1);
        unsigned short l0 = bf16_rne(v0 - bf16_f(h0));
        unsigned short l1 = bf16_rne(v1 - bf16_f(h1));
        ((unsigned*)W2Ph)[(size_t)c * 32 + dp] =
            (unsigned)h0 | ((unsigned)h1 << 16);
        ((unsigned*)W2Pl)[(size_t)c * 32 + dp] =
            (unsigned)l0 | ((unsigned)l1 << 16);
      }
    }
  }
}

// ---------------------------------------------------------------------------
// Kernel 1r (11 blocks):
//   block 0: cursor zero + parallel count reduce + segment bases + tinfo
//   blocks 1..10: S1g reduce, 64 cols each, 4 waves x 98 coalesced loads
// ---------------------------------------------------------------------------
__global__ __launch_bounds__(256) void k1r(
    const float* __restrict__ S1p, const float* __restrict__ cntp,
    float* __restrict__ S1g, float* __restrict__ cntF, int* __restrict__ meta,
    int* __restrict__ tinfo, int* __restrict__ cursor) {
  int t = threadIdx.x;
  if (blockIdx.x > 0) {                        // ---- S1g chunk reduce ----
    __shared__ float sgp[4][64];
    int wave = t >> 6, lane = t & 63;
    int col = (blockIdx.x - 1) * 64 + lane;
    float s = 0.f;
    const float* sp = S1p + col;
#pragma unroll 4
    for (int b = wave; b < K1B; b += 4) s += sp[b * 640];
    sgp[wave][lane] = s;
    __syncthreads();
    if (t < 64) {
      S1g[(blockIdx.x - 1) * 64 + t] =
          sgp[0][t] + sgp[1][t] + sgp[2][t] + sgp[3][t];
    }
    return;
  }
  __shared__ int baseS[11];
  __shared__ int cntI[N_CLUSTERS];
  __shared__ float part[16][N_CLUSTERS];
  if (t < 16) cursor[t] = 0;
  if (t < 160) {                               // coalesced count reduce
    int c = t % N_CLUSTERS, g = t / N_CLUSTERS;
    float s = 0.f;
    for (int b = g; b < K1B; b += 16) s += cntp[b * N_CLUSTERS + c];
    part[g][c] = s;
  }
  __syncthreads();
  if (t < N_CLUSTERS) {
    float s = 0.f;
#pragma unroll
    for (int g = 0; g < 16; ++g) s += part[g][t];
    cntF[t] = s;
    cntI[t] = (int)(s + 0.5f);
  }
  __syncthreads();
  if (t == 0) {
    int acc = 0;
    for (int c = 0; c < N_CLUSTERS; ++c) {
      baseS[c] = acc;
      acc += ((cntI[c] + 15) >> 4) << 4;       // 16-align each segment
    }
    baseS[10] = acc;
    for (int c = 0; c < 11; ++c) meta[c] = baseS[c];
    meta[11] = acc >> 4;                       // NT
  }
  __syncthreads();
  int NT = baseS[10] >> 4;
  for (int jt = t; jt < MAXT; jt += 256) {
    int c = 0, nv = 0;
    if (jt < NT) {
      int p0 = jt * 16;
      for (int k = 0; k < N_CLUSTERS; ++k)
        if (p0 >= baseS[k] && p0 < baseS[k + 1]) c = k;
      nv = min(16, cntI[c] - (p0 - baseS[c]));
      if (nv < 0) nv = 0;
    }
    tinfo[jt] = c | (nv << 8);
  }
}

// ---------------------------------------------------------------------------
// Kernel B (fused): blocks [0,391) = inverse perm + bucket zero;
// blocks [391,423) = A-fragment precompute for 64-ROW tiles (R3 layout:
// 16 bx x 16 frags x 64 lanes; h = inp @ S1g, *log2e, RNE hi/lo split).
// ---------------------------------------------------------------------------
__global__ __launch_bounds__(256) void kB(
    const int* __restrict__ cl, const int* __restrict__ meta,
    int* __restrict__ cursor, int* __restrict__ inv,
    const float* __restrict__ inp, const float* __restrict__ S1g,
    short8* __restrict__ hfrag, float* __restrict__ bucket) {
  __shared__ int wn[4][N_CLUSTERS];
  __shared__ int bb[N_CLUSTERS];
  int t = threadIdx.x;
  if (blockIdx.x < 391) {
    int i = blockIdx.x * 256 + t;
    if (i < N_B * N_CLUSTERS) bucket[i] = 0.f;
    int wave = t >> 6, lane = t & 63;
    int c = (i < N_ITEMS) ? cl[i] : -1;
    unsigned long long m[N_CLUSTERS];
#pragma unroll
    for (int k = 0; k < N_CLUSTERS; ++k) {
      m[k] = __ballot(c == k);
      if (lane == 0) wn[wave][k] = __popcll(m[k]);
    }
    __syncthreads();
    if (t < N_CLUSTERS) {
      int tot = wn[0][t] + wn[1][t] + wn[2][t] + wn[3][t];
      bb[t] = tot ? atomicAdd(&cursor[t], tot) : 0;
    }
    __syncthreads();
    if (c >= 0) {
      int rank = 0;
#pragma unroll
      for (int k = 0; k < N_CLUSTERS; ++k)
        if (c == k) rank = __popcll(m[k] & ((1ull << lane) - 1ull));
      int wsum = 0;
      for (int w2 = 0; w2 < wave; ++w2) wsum += wn[w2][c];
      inv[meta[c] + bb[c] + wsum + rank] = i;
    }
  } else {
    int id = (blockIdx.x - 391) * 256 + t;     // 8192 (bx,rt,ks,lane) tuples
    int lane = id & 63;
    int ks = (id >> 6) & 1;
    int rt = (id >> 7) & 3;
    int bx = id >> 9;                          // 0..15
    int row = bx * 64 + rt * 16 + (lane & 15);
    int d0 = ks * 32 + (lane >> 4) * 8;
    float hv[8];
#pragma unroll
    for (int j = 0; j < 8; ++j) hv[j] = 0.f;
#pragma unroll
    for (int c = 0; c < N_CLUSTERS; ++c) {
      float ic = inp[row * N_CLUSTERS + c];
      const float* sp = S1g + c * N_D + d0;
#pragma unroll
      for (int j = 0; j < 8; ++j) hv[j] += ic * sp[j];
    }
    short8 hi8, lo8;
#pragma unroll
    for (int j = 0; j < 8; ++j) {
      float x = hv[j] * 1.44269504088896340736f;   // fold log2(e) -> exp2
      unsigned short us = bf16_rne(x);
      hi8[j] = (short)us;
      lo8[j] = (short)bf16_rne(x - bf16_f(us));
    }
    int f0 = rt * 4 + ks * 2;
    hfrag[(bx * 16 + f0) * 64 + lane] = hi8;
    hfrag[(bx * 16 + f0 + 1) * 64 + lane] = lo8;
  }
}

// ---------------------------------------------------------------------------
// Kernel 3 (hot) — R3 configuration (proven 62us): 64-row wave-tiles,
// fr[16] in regs, 24 MFMA/visit, grid 16x48=768, launch_bounds(256,3)
// (~170 unified regs, no spill, 3 waves/SIMD). R4/R5 (reg caps) and R6
// (32-row tiles) each probed one direction off this point and lost.
// ---------------------------------------------------------------------------
__global__ __launch_bounds__(256, 3) void k3_mfma(
    const unsigned short* __restrict__ W2Ph,
    const unsigned short* __restrict__ W2Pl,
    const short8* __restrict__ hfrag, const int* __restrict__ inv,
    const int* __restrict__ tinfo, float* __restrict__ bucket) {
  __shared__ int linv[4][544];                 // 33*16=528 used, 8.7 KB
  int t = threadIdx.x;
  int wave = t >> 6, lane = t & 63;
  int l15 = lane & 15, quad = lane >> 4;

  // bijective XCD swizzle: 768 = 8 XCDs x 96; same-by 16-block groups land
  // on one XCD (shared B tiles -> L2 hits)
  int lid = blockIdx.y * 16 + blockIdx.x;
  int nid = (lid & 7) * 96 + (lid >> 3);
  int bx = nid & 15, by = nid >> 4;            // by 0..47

  int gw = by * 4 + wave;                      // 0..191
  int jt0 = (MAXT * gw) / NGW;
  int nt = (MAXT * (gw + 1)) / NGW - jt0;      // 32 or 33

  // A fragments -> registers (invariant across this wave's tiles)
  short8 fr[16];
  {
    const short8* hp = hfrag + bx * 1024 + lane;
#pragma unroll
    for (int f = 0; f < 16; ++f) fr[f] = hp[f * 64];
  }
  // tinfo slice -> lane registers (readlane broadcast later)
  int tiv = tinfo[jt0 + ((lane < nt) ? lane : nt - 1)];
  // stage this wave's col slice into LDS
  {
    const int* ip = inv + jt0 * 16;
    int n = nt * 16;
    for (int i = lane; i < n; i += 64) linv[wave][i] = ip[i];
  }
  __syncthreads();

  f32x4 acc[4];
#pragma unroll
  for (int r = 0; r < 4; ++r) acc[r] = (f32x4){0.f, 0.f, 0.f, 0.f};

  short8 xh0, xl0, xh1, xl1, yh0, yl0, yh1, yl1;
  int cc, nv, colN;
  {
    int c0 = inv[jt0 * 16 + l15];
    int o = c0 * 64 + quad * 8;
    xh0 = *(const short8*)(W2Ph + o);
    xh1 = *(const short8*)(W2Ph + o + 32);
    xl0 = *(const short8*)(W2Pl + o);
    xl1 = *(const short8*)(W2Pl + o + 32);
    colN = inv[jt0 * 16 + 16 + l15];           // tile 1 (nt >= 32 always)
    int ti = __builtin_amdgcn_readlane(tiv, 0);
    cc = ti & 255;
    nv = ti >> 8;
  }

#define K3_FLUSH()                                                            \
  {                                                                           \
    _Pragma("unroll") for (int rt = 0; rt < 4; ++rt) {                        \
      float e0 = acc[rt][0], e1 = acc[rt][1];                                 \
      float e2 = acc[rt][2], e3 = acc[rt][3];                                 \
      _Pragma("unroll") for (int mm = 1; mm < 16; mm <<= 1) {                 \
        e0 += __shfl_xor(e0, mm, 64);                                         \
        e1 += __shfl_xor(e1, mm, 64);                                         \
        e2 += __shfl_xor(e2, mm, 64);                                         \
        e3 += __shfl_xor(e3, mm, 64);                                         \
      }                                                                       \
      if (l15 == 0) {                                                         \
        int r = bx * 64 + rt * 16 + quad * 4;                                 \
        atomicAdd(&bucket[(r + 0) * N_CLUSTERS + cc], e0);                    \
        atomicAdd(&bucket[(r + 1) * N_CLUSTERS + cc], e1);                    \
        atomicAdd(&bucket[(r + 2) * N_CLUSTERS + cc], e2);                    \
        atomicAdd(&bucket[(r + 3) * N_CLUSTERS + cc], e3);                    \
      }                                                                       \
      acc[rt] = (f32x4){0.f, 0.f, 0.f, 0.f};                                  \
    }                                                                         \
  }

#define K3_PHASE(CH0, CL0, CH1, CL1, NH0, NL0, NH1, NL1)                      \
  {                                                                           \
    int tin = __builtin_amdgcn_readlane(tiv, (it + 1 < nt) ? it + 1 : nt - 1);\
    int ccn = tin & 255, nvn = tin >> 8;                                      \
    {                                                                         \
      int o = colN * 64 + quad * 8;            /* prefetch tile it+1 */       \
      NH0 = *(const short8*)(W2Ph + o);                                       \
      NH1 = *(const short8*)(W2Ph + o + 32);                                  \
      NL0 = *(const short8*)(W2Pl + o);                                       \
      NL1 = *(const short8*)(W2Pl + o + 32);                                  \
    }                                                                         \
    colN = linv[wave][((it + 2 < nt) ? it + 2 : nt - 1) * 16 + l15];          \
    f32x4 cr[4];                                                              \
    _Pragma("unroll") for (int rt = 0; rt < 4; ++rt) {                        \
      f32x4 c = {0.f, 0.f, 0.f, 0.f};                                         \
      c = MFMA(fr[rt * 4 + 0], CH0, c);                                       \
      c = MFMA(fr[rt * 4 + 0], CL0, c);                                       \
      c = MFMA(fr[rt * 4 + 1], CH0, c);                                       \
      c = MFMA(fr[rt * 4 + 2], CH1, c);                                       \
      c = MFMA(fr[rt * 4 + 2], CL1, c);                                       \
      c = MFMA(fr[rt * 4 + 3], CH1, c);                                       \
      cr[rt] = c;                                                             \
    }                                                                         \
    if (nv == 16) {                                                           \
      _Pragma("unroll") for (int rt = 0; rt < 4; ++rt) {                      \
        acc[rt][0] += EXP2F(cr[rt][0]);                                       \
        acc[rt][1] += EXP2F(cr[rt][1]);                                       \
        acc[rt][2] += EXP2F(cr[rt][2]);                                       \
        acc[rt][3] += EXP2F(cr[rt][3]);                                       \
      }                                                                       \
    } else {                                                                  \
      _Pragma("unroll") for (int rt = 0; rt < 4; ++rt) {                      \
        acc[rt][0] += (l15 < nv) ? EXP2F(cr[rt][0]) : 0.f;                    \
        acc[rt][1] += (l15 < nv) ? EXP2F(cr[rt][1]) : 0.f;                    \
        acc[rt][2] += (l15 < nv) ? EXP2F(cr[rt][2]) : 0.f;                    \
        acc[rt][3] += (l15 < nv) ? EXP2F(cr[rt][3]) : 0.f;                    \
      }                                                                       \
    }                                                                         \
    if (it == nt - 1 || ccn != cc) K3_FLUSH();                                \
    cc = ccn;                                                                 \
    nv = nvn;                                                                 \
    ++it;                                                                     \
    if (it == nt) break;                                                      \
  }

  int it = 0;
  while (true) {
    K3_PHASE(xh0, xl0, xh1, xl1, yh0, yl0, yh1, yl1)
    K3_PHASE(yh0, yl0, yh1, yl1, xh0, xl0, xh1, xl1)
  }
#undef K3_PHASE
#undef K3_FLUSH
}

// ---------------------------------------------------------------------------
// Kernel 4: normalize (softmax denom = per-row sum over clusters), /counts.
// ---------------------------------------------------------------------------
__global__ __launch_bounds__(320) void k4_fin(
    const float* __restrict__ bucket, const float* __restrict__ cntF,
    float* __restrict__ out) {
  __shared__ float bl[32][N_CLUSTERS];
  int t = threadIdx.x;                         // 0..319
  int r = t / N_CLUSTERS, c = t % N_CLUSTERS;
  int row = blockIdx.x * 32 + r;
  float s = bucket[row * N_CLUSTERS + c];
  bl[r][c] = s;
  __syncthreads();
  float tot = 0.f;
#pragma unroll
  for (int k = 0; k < N_CLUSTERS; ++k) tot += bl[r][k];
  out[row * N_CLUSTERS + c] = s / (tot * fmaxf(cntF[c], 1.f));
}

// ---------------------------------------------------------------------------
// Workspace layout (4-byte units), total 27.7 MB:
//   [0,640) S1g | [640,656) cntF | [656,672) meta | [672,688) cursor
//   [1024,7296) tinfo = cluster|(nv<<8) | [16384,116736) inv
//   [131072,196608) hfrag (256 KB, MFMA A layout, log2e folded)
//   [262144,3463168) W2Ph (bf16 hi plane, item-major)
//   [3463168,6664192) W2Pl (bf16 lo plane)
//   [6664192,6915072) S1p | [6915072,6918992) cntp
//   [6918992,6929232) bucket (atomic accum; zeroed in kB)
// No memset: inv zeroed by kA, cursor by k1r, bucket by kB.
// ---------------------------------------------------------------------------
extern "C" void kernel_launch(void* const* d_in, const int* in_sizes, int n_in,
                              void* d_out, int out_size, void* d_ws, size_t ws_size,
                              hipStream_t stream) {
  const float* input = (const float*)d_in[0];   // (1024, 10) f32
  const int* cl      = (const int*)d_in[1];     // (100000,) i32
  const float* W1    = (const float*)d_in[2];   // (100000, 64) f32
  const float* W2    = (const float*)d_in[3];   // (64, 100000) f32
  float* out = (float*)d_out;
  float* ws = (float*)d_ws;

  float* S1g            = ws;
  float* cntF           = ws + 640;
  int*   meta           = (int*)(ws + 656);
  int*   cursor         = (int*)(ws + 672);
  int*   tinfo          = (int*)(ws + 1024);
  int*   inv            = (int*)(ws + 16384);
  short8* hfrag         = (short8*)(ws + 131072);
  unsigned short* W2Ph  = (unsigned short*)(ws + 262144);
  unsigned short* W2Pl  = (unsigned short*)(ws + 3463168);
  float* S1p            = ws + 6664192;
  float* cntp           = ws + 6915072;
  float* bucket         = ws + 6918992;

  kA<<<K1B + W2PB, 256, 0, stream>>>(cl, W1, W2, S1p, cntp, inv, W2Ph, W2Pl);
  k1r<<<11, 256, 0, stream>>>(S1p, cntp, S1g, cntF, meta, tinfo, cursor);
  kB<<<391 + 32, 256, 0, stream>>>(cl, meta, cursor, inv, input, S1g, hfrag,
                                   bucket);
  dim3 g3(16, K3BY);                            // 768 blocks = 3/CU
  k3_mfma<<<g3, 256, 0, stream>>>(W2Ph, W2Pl, hfrag, inv, tinfo, bucket);
  k4_fin<<<32, 320, 0, stream>>>(bucket, cntF, out);
}